// Round 10
// baseline (214.868 us; speedup 1.0000x reference)
//
#include <hip/hip_runtime.h>
#include <math.h>

// Problem constants
#define NNODES 100000
#define NEDGES 500000
#define HID    256
#define K2     512
#define GEMM_GRID 256
#define MT2    32                       // gemm tile rows (100000 = 3125*32 exact)
#define NT2    3125

typedef _Float16 h8v __attribute__((ext_vector_type(8)));
typedef _Float16 h2v __attribute__((ext_vector_type(2)));
typedef __bf16   bf16x8 __attribute__((ext_vector_type(8)));
typedef float    f32x4  __attribute__((ext_vector_type(4)));
typedef float    f32x2  __attribute__((ext_vector_type(2)));

__device__ __forceinline__ unsigned short f2bf(float f) {
    unsigned int u = __float_as_uint(f);
    u += 0x7FFFu + ((u >> 16) & 1u);
    return (unsigned short)(u >> 16);
}

// async global->LDS 16B DMA (zero staging VGPRs).
__device__ __forceinline__ void gload16(const float* g, const float* lds_base_uniform) {
    typedef const __attribute__((address_space(1))) unsigned int ga_u32;
    typedef __attribute__((address_space(3))) unsigned int lds_u32;
    __builtin_amdgcn_global_load_lds((ga_u32*)(uintptr_t)g,
                                     (lds_u32*)(unsigned int)(uintptr_t)lds_base_uniform,
                                     16, 0, 0);
}

// ---- W1 [256][512] fp32 -> Bsw fp16 fragment order (K=256, N=512) ----------
__global__ void cvt_w1h(const float* __restrict__ W1, _Float16* __restrict__ Bsw) {
    int t = blockIdx.x * 256 + threadIdx.x;                  // 8*32*64 = 16384 units
    if (t >= 8 * 32 * 64) return;
    int lane = t & 63, nt = (t >> 6) & 31, kt = t >> 11;
    int j = nt * 16 + (lane & 15);
    int k = kt * 32 + ((lane >> 4) << 3);
    const float* src = W1 + (size_t)(j & 255) * K2 + ((j >> 8) << 8) + k;
    union { _Float16 s[8]; uint4 v; } u;
#pragma unroll
    for (int jj = 0; jj < 8; ++jj) u.s[jj] = (_Float16)src[jj];
    ((uint4*)Bsw)[t] = u.v;
}

// ---- node GEMM v11: 16 waves/block (4 waves/SIMD), fp8 UV, DMA pipeline ----
// v10 post-mortem: 50us at a 24us BW floor with 2 waves/SIMD — latency-hiding
// starved. 16 waves x 32 cols: barr halves to 64 VGPR/wave -> fits the
// 128-VGPR/4-wave budget. Stored byte t = w*32 + i*2 + ntl <-> hidden col
// w*32 + ntl*16 + i  => col(t) = (t&~31)|((t&1)<<4)|((t>>1)&15).
__global__ __launch_bounds__(1024, 1) void node_gemm11(
    const float* __restrict__ x,
    const _Float16* __restrict__ Bsw,
    const float* __restrict__ b1,
    unsigned char* __restrict__ UV8)
{
    __shared__ __align__(16) float A0[MT2 * 256];            // 32 KB
    __shared__ __align__(16) float A1[MT2 * 256];            // 32 KB
    const int tid  = threadIdx.x;
    const int lane = tid & 63;
    const int wave = tid >> 6;                               // 0..15

    // ---- B into registers (once): wave owns stored cols [wave*32, +32) ----
    const h8v* B8 = (const h8v*)Bsw;
    h8v barr[8][2];
#pragma unroll
    for (int ks = 0; ks < 8; ++ks)
#pragma unroll
        for (int ntl = 0; ntl < 2; ++ntl)
            barr[ks][ntl] = B8[((size_t)(ks * 32 + wave * 2 + ntl)) * 64 + lane];

    float b1v[2];
#pragma unroll
    for (int ntl = 0; ntl < 2; ++ntl) {
        int col = wave * 32 + ntl * 16 + (lane & 15);        // true hidden col
        b1v[ntl] = (col < 256) ? b1[col] : 0.0f;
    }

    // stage: each wave DMAs 2 rows (1KB each); XOR-swizzled global source.
    auto stage = [&](int t, float* dstb) {
#pragma unroll
        for (int i = 0; i < 2; ++i) {
            int row = wave * 2 + i;                          // 0..31, wave-uniform
            int u   = lane ^ (row & 7);                      // pre-swizzled source
            const float* src = x + (size_t)(t * MT2 + row) * 256 + u * 4;
            gload16(src, dstb + row * 256);                  // uniform base; HW adds lane*16
        }
    };

    // compute tile from Abuf + store UV8 rows [t*32, t*32+32)
    auto work = [&](const float* Ab, int t) {
        const f32x4* A4 = (const f32x4*)Ab;
        f32x4 acc[2][2] = {};
#pragma unroll
        for (int ks = 0; ks < 8; ++ks) {
            h8v af[2];
#pragma unroll
            for (int mt = 0; mt < 2; ++mt) {
                int row = mt * 16 + (lane & 15);
                int u0  = ks * 8 + ((lane >> 4) << 1);
                f32x4 lo = A4[row * 64 + ( u0      ^ (row & 7))];
                f32x4 hi = A4[row * 64 + ((u0 + 1) ^ (row & 7))];
                af[mt] = h8v{(_Float16)lo[0], (_Float16)lo[1], (_Float16)lo[2], (_Float16)lo[3],
                             (_Float16)hi[0], (_Float16)hi[1], (_Float16)hi[2], (_Float16)hi[3]};
            }
#pragma unroll
            for (int mt = 0; mt < 2; ++mt)
#pragma unroll
                for (int ntl = 0; ntl < 2; ++ntl)
                    acc[mt][ntl] = __builtin_amdgcn_mfma_f32_16x16x32_f16(
                        af[mt], barr[ks][ntl], acc[mt][ntl], 0, 0, 0);
        }
        // store: 2 stored-cols per row per lane -> one fp8-packed ushort
#pragma unroll
        for (int mt = 0; mt < 2; ++mt) {
#pragma unroll
            for (int r = 0; r < 4; ++r) {
                int row = t * MT2 + mt * 16 + ((lane >> 4) << 2) + r;
                float h0 = acc[mt][0][r] + b1v[0];
                float h1 = acc[mt][1][r] + b1v[1];
                int w = __builtin_amdgcn_cvt_pk_fp8_f32(h0, h1, 0, false);
                *(unsigned short*)(UV8 + (size_t)row * 512 + wave * 32 + (lane & 15) * 2)
                    = (unsigned short)w;
            }
        }
    };

    int tile = blockIdx.x;                                   // grid 256 <= NT2 always
    stage(tile, A0);
    __syncthreads();                                         // drain: A0 ready

    for (;;) {
        int n1 = tile + GEMM_GRID;
        if (n1 < NT2) stage(n1, A1);                         // DMA flies under work(A0)
        work(A0, tile);
        if (n1 >= NT2) return;
        __syncthreads();                                     // A1 ready; A0 reads done

        int n2 = n1 + GEMM_GRID;
        if (n2 < NT2) stage(n2, A0);
        work(A1, n1);
        if (n2 >= NT2) return;
        __syncthreads();                                     // A0 ready; A1 reads done
        tile = n2;
    }
}

// ---- edge pass v7: fp8 UV, all-f32 MLP; col(t) for the v11 store layout ----
__global__ __launch_bounds__(256) void edge_out7(
    const unsigned char* __restrict__ UV8,
    const int* __restrict__ ei,
    const float* __restrict__ W2,
    const float* __restrict__ b2,
    float* __restrict__ out)
{
    const int tid = threadIdx.x;
    const int q   = tid & 31;
    const int g   = tid >> 5;
    long e = (long)blockIdx.x * 64 + g * 8;
    if (e > NEDGES - 8) e = NEDGES - 8;                      // clamp (dup writes benign)

    int4 sa = *(const int4*)(ei + e);
    int4 sb = *(const int4*)(ei + e + 4);
    int4 da = *(const int4*)(ei + NEDGES + e);
    int4 db = *(const int4*)(ei + NEDGES + e + 4);

    float w2f[8];
#pragma unroll
    for (int jj = 0; jj < 8; ++jj) {
        int t   = q * 8 + jj;
        int col = (t & ~31) | (((t & 1) << 4) | ((t >> 1) & 15));
        w2f[jj] = W2[col];
    }

    const unsigned char* up = UV8 + q * 8;

    int s[8] = {sa.x, sa.y, sa.z, sa.w, sb.x, sb.y, sb.z, sb.w};
    int d[8] = {da.x, da.y, da.z, da.w, db.x, db.y, db.z, db.w};

    uint2 uu[8], vv[8];
#pragma unroll
    for (int ed = 0; ed < 8; ++ed) {
        uu[ed] = *(const uint2*)(up + (size_t)s[ed] * 512);
        vv[ed] = *(const uint2*)(up + (size_t)d[ed] * 512 + 256);
    }

    float z[8] = {};
#pragma unroll
    for (int ed = 0; ed < 8; ++ed) {
        f32x2 u01 = __builtin_amdgcn_cvt_pk_f32_fp8((int)uu[ed].x, false);
        f32x2 u23 = __builtin_amdgcn_cvt_pk_f32_fp8((int)uu[ed].x, true);
        f32x2 u45 = __builtin_amdgcn_cvt_pk_f32_fp8((int)uu[ed].y, false);
        f32x2 u67 = __builtin_amdgcn_cvt_pk_f32_fp8((int)uu[ed].y, true);
        f32x2 v01 = __builtin_amdgcn_cvt_pk_f32_fp8((int)vv[ed].x, false);
        f32x2 v23 = __builtin_amdgcn_cvt_pk_f32_fp8((int)vv[ed].x, true);
        f32x2 v45 = __builtin_amdgcn_cvt_pk_f32_fp8((int)vv[ed].y, false);
        f32x2 v67 = __builtin_amdgcn_cvt_pk_f32_fp8((int)vv[ed].y, true);
        float h[8];
        h[0] = u01[0] + v01[0]; h[1] = u01[1] + v01[1];
        h[2] = u23[0] + v23[0]; h[3] = u23[1] + v23[1];
        h[4] = u45[0] + v45[0]; h[5] = u45[1] + v45[1];
        h[6] = u67[0] + v67[0]; h[7] = u67[1] + v67[1];
        float acc = 0.f;
#pragma unroll
        for (int jj = 0; jj < 8; ++jj)
            acc = fmaf(fmaxf(h[jj], 0.0f), w2f[jj], acc);
        z[ed] = acc;
    }
#pragma unroll
    for (int m = 1; m < 32; m <<= 1) {
#pragma unroll
        for (int ed = 0; ed < 8; ++ed)
            z[ed] += __shfl_xor(z[ed], m, 32);
    }
    if (q < 8) {
        float zq = z[0];
#pragma unroll
        for (int ed = 1; ed < 8; ++ed)
            if (q == ed) zq = z[ed];
        out[e + q] = 1.0f / (1.0f + expf(-(zq + b2[0])));
    }
}

// ======================= minimal fallback (tiny ws) =========================
__global__ void cvt_w1_r1(const float* __restrict__ W1, unsigned short* __restrict__ Bsw) {
    int t = blockIdx.x * 256 + threadIdx.x;
    if (t >= 16 * 16 * 64) return;
    int lane = t & 63, nt = (t >> 6) & 15, kt = t >> 10;
    int n = nt * 16 + (lane & 15);
    int k = kt * 32 + ((lane >> 4) << 3);
    const float* src = W1 + (size_t)n * K2 + k;
    union { unsigned short s[8]; uint4 v; } u;
#pragma unroll
    for (int j = 0; j < 8; ++j) u.s[j] = f2bf(src[j]);
    ((uint4*)Bsw)[t] = u.v;
}

__global__ __launch_bounds__(256) void edge_mlp_fb(
    const float* __restrict__ xf, const int* __restrict__ ei,
    const unsigned short* __restrict__ Bsw, const float* __restrict__ b1,
    const float* __restrict__ W2, const float* __restrict__ b2,
    float* __restrict__ out)
{
    __shared__ __align__(16) unsigned short Asw[8 * 4 * 64 * 8];
    __shared__ float es[64];
    const int tid = threadIdx.x, lane = tid & 63, wave = tid >> 6;
    const int e0 = blockIdx.x * 64;
    if (tid < 64) es[tid] = 0.0f;
    f32x4 acc[4][4] = {};
    const bf16x8* A8 = (const bf16x8*)Asw;
    const bf16x8* B8 = (const bf16x8*)Bsw;
    for (int h = 0; h < 2; ++h) {
#pragma unroll
        for (int i = 0; i < 8; ++i) {
            int m = i * 8 + wave * 2 + (lane >> 5);
            int e = e0 + m;
            int ee = (e < NEDGES) ? e : 0;
            int node = ei[(size_t)h * NEDGES + ee];
            int chunk = lane & 31;
            const float4* p = (const float4*)(xf + ((size_t)node << 8) + (chunk << 3));
            float4 a = p[0], bq = p[1];
            union { unsigned short s[8]; uint4 v4; } u;
            u.s[0] = f2bf(a.x);  u.s[1] = f2bf(a.y);  u.s[2] = f2bf(a.z);  u.s[3] = f2bf(a.w);
            u.s[4] = f2bf(bq.x); u.s[5] = f2bf(bq.y); u.s[6] = f2bf(bq.z); u.s[7] = f2bf(bq.w);
            int ktl = chunk >> 2, qq = chunk & 3;
            int u16 = ((ktl * 4 + (m >> 4)) << 6) + (qq << 4) + (m & 15);
            u16 ^= (u16 >> 8) & 7;
            ((uint4*)Asw)[u16] = u.v4;
        }
        __syncthreads();
#pragma unroll
        for (int kt = 0; kt < 8; ++kt) {
            bf16x8 af[4], bfr[4];
#pragma unroll
            for (int mt = 0; mt < 4; ++mt) {
                int u16 = ((kt * 4 + mt) << 6) + lane;
                u16 ^= (u16 >> 8) & 7;
                af[mt] = A8[u16];
            }
#pragma unroll
            for (int nt = 0; nt < 4; ++nt)
                bfr[nt] = B8[(((h * 8 + kt) << 4) + (wave << 2) + nt) * 64 + lane];
#pragma unroll
            for (int mt = 0; mt < 4; ++mt)
#pragma unroll
                for (int nt = 0; nt < 4; ++nt)
                    acc[mt][nt] = __builtin_amdgcn_mfma_f32_16x16x32_bf16(
                        af[mt], bfr[nt], acc[mt][nt], 0, 0, 0);
        }
        __syncthreads();
    }
    float w2v[4], b1v[4];
#pragma unroll
    for (int nt = 0; nt < 4; ++nt) {
        int n = (wave << 6) + (nt << 4) + (lane & 15);
        w2v[nt] = W2[n]; b1v[nt] = b1[n];
    }
#pragma unroll
    for (int mt = 0; mt < 4; ++mt) {
#pragma unroll
        for (int r = 0; r < 4; ++r) {
            float p = 0.0f;
#pragma unroll
            for (int nt = 0; nt < 4; ++nt) {
                float hv = acc[mt][nt][r] + b1v[nt];
                p = fmaf(fmaxf(hv, 0.0f), w2v[nt], p);
            }
            p += __shfl_xor(p, 1, 16);
            p += __shfl_xor(p, 2, 16);
            p += __shfl_xor(p, 4, 16);
            p += __shfl_xor(p, 8, 16);
            if ((lane & 15) == 0)
                atomicAdd(&es[(mt << 4) + ((lane >> 4) << 2) + r], p);
        }
    }
    __syncthreads();
    if (tid < 64) {
        int e = e0 + tid;
        if (e < NEDGES) out[e] = 1.0f / (1.0f + expf(-(es[tid] + b2[0])));
    }
}

// ============================== launch ======================================
extern "C" void kernel_launch(void* const* d_in, const int* in_sizes, int n_in,
                              void* d_out, int out_size, void* d_ws, size_t ws_size,
                              hipStream_t stream) {
    const float* x  = (const float*)d_in[0];
    const int*   ei = (const int*)d_in[1];
    const float* W1 = (const float*)d_in[2];
    const float* b1 = (const float*)d_in[3];
    const float* W2 = (const float*)d_in[4];
    const float* b2 = (const float*)d_in[5];
    float* out = (float*)d_out;

    const size_t BSW_BYTES = 1 << 18;                           // 256 KB
    const size_t UV8_BYTES = (size_t)NNODES * 512;              // 51.2 MB fp8
    const size_t NEED_A = BSW_BYTES + UV8_BYTES;

    if (ws_size >= NEED_A) {
        _Float16*      Bsw = (_Float16*)d_ws;
        unsigned char* UV8 = (unsigned char*)d_ws + BSW_BYTES;
        cvt_w1h<<<64, 256, 0, stream>>>(W1, Bsw);
        node_gemm11<<<GEMM_GRID, 1024, 0, stream>>>(x, Bsw, b1, UV8);
        edge_out7<<<(NEDGES + 63) / 64, 256, 0, stream>>>(UV8, ei, W2, b2, out);
    } else {
        unsigned short* Bsw = (unsigned short*)d_ws;
        cvt_w1_r1<<<64, 256, 0, stream>>>(W1, Bsw);
        edge_mlp_fb<<<(NEDGES + 63) / 64, 256, 0, stream>>>(x, ei, Bsw, b1, W2, b2, out);
    }
}

// Round 11
// 204.217 us; speedup vs baseline: 1.0522x; 1.0522x over previous
//
#include <hip/hip_runtime.h>
#include <math.h>

// Problem constants
#define NNODES 100000
#define NEDGES 500000
#define HID    256
#define K2     512
#define GEMM_GRID 256
#define MT2    32                       // gemm tile rows (100000 = 3125*32 exact)
#define NT2    3125

typedef _Float16 h8v __attribute__((ext_vector_type(8)));
typedef _Float16 h2v __attribute__((ext_vector_type(2)));
typedef __bf16   bf16x8 __attribute__((ext_vector_type(8)));
typedef float    f32x4  __attribute__((ext_vector_type(4)));
typedef float    f32x2  __attribute__((ext_vector_type(2)));

__device__ __forceinline__ unsigned short f2bf(float f) {
    unsigned int u = __float_as_uint(f);
    u += 0x7FFFu + ((u >> 16) & 1u);
    return (unsigned short)(u >> 16);
}

// ---- W1 [256][512] fp32 -> Bsw fp16 fragment order (K=256, N=512) ----------
__global__ void cvt_w1h(const float* __restrict__ W1, _Float16* __restrict__ Bsw) {
    int t = blockIdx.x * 256 + threadIdx.x;                  // 8*32*64 = 16384 units
    if (t >= 8 * 32 * 64) return;
    int lane = t & 63, nt = (t >> 6) & 31, kt = t >> 11;
    int j = nt * 16 + (lane & 15);
    int k = kt * 32 + ((lane >> 4) << 3);
    const float* src = W1 + (size_t)(j & 255) * K2 + ((j >> 8) << 8) + k;
    union { _Float16 s[8]; uint4 v; } u;
#pragma unroll
    for (int jj = 0; jj < 8; ++jj) u.s[jj] = (_Float16)src[jj];
    ((uint4*)Bsw)[t] = u.v;
}

// ---- node GEMM v12: 16 waves, fp16 A in LDS (reg-staged, T14 split) --------
// v11 post-mortem: fp32 LDS + 16 waves doubled LDS reads (512 b128/tile) and
// work-loop cvt -> LDS/VALU bound. v12: A staged as fp16 -> 1 ds_read per
// fragment (256 reads/tile, v10 count at v11 occupancy), cvt at stage time,
// XOR-swizzled units (conflict-free), 2x16KB LDS. VGPR fits the 128 pin:
// barr 64 + acc 16 + stage 12 + misc ~= 115.
// Stored byte t = w*32 + i*2 + ntl <-> hidden col w*32 + ntl*16 + i
// => col(t) = (t&~31)|((t&1)<<4)|((t>>1)&15)  (edge_out7 compensates).
__global__ __launch_bounds__(1024, 1) void node_gemm12(
    const float* __restrict__ x,
    const _Float16* __restrict__ Bsw,
    const float* __restrict__ b1,
    unsigned char* __restrict__ UV8)
{
    __shared__ __align__(16) _Float16 A0h[MT2 * 256];        // 16 KB
    __shared__ __align__(16) _Float16 A1h[MT2 * 256];        // 16 KB
    const int tid  = threadIdx.x;
    const int lane = tid & 63;
    const int wave = tid >> 6;                               // 0..15

    // ---- B into registers (once): wave owns stored cols [wave*32, +32) ----
    const h8v* B8 = (const h8v*)Bsw;
    h8v barr[8][2];
#pragma unroll
    for (int ks = 0; ks < 8; ++ks)
#pragma unroll
        for (int ntl = 0; ntl < 2; ++ntl)
            barr[ks][ntl] = B8[((size_t)(ks * 32 + wave * 2 + ntl)) * 64 + lane];

    float b1v[2];
#pragma unroll
    for (int ntl = 0; ntl < 2; ++ntl) {
        int col = wave * 32 + ntl * 16 + (lane & 15);        // true hidden col
        b1v[ntl] = (col < 256) ? b1[col] : 0.0f;
    }

    // staging regs: wave covers rows {wave*2, wave*2+1}; lane -> 32B fp32
    const int srow = wave * 2 + (lane >> 5);                 // 0..31
    const int sc   = lane & 31;                              // fp32 col /8
    float4 xa, xb;

    auto load_regs = [&](int t) {                            // issue-early
        const float4* p = (const float4*)(x + (size_t)(t * MT2 + srow) * 256 + sc * 8);
        xa = p[0]; xb = p[1];
    };
    auto put_tile = [&](_Float16* dstb) {                    // write-late (cvt here)
        union { _Float16 s[8]; uint4 v; } u;
        u.s[0] = (_Float16)xa.x; u.s[1] = (_Float16)xa.y;
        u.s[2] = (_Float16)xa.z; u.s[3] = (_Float16)xa.w;
        u.s[4] = (_Float16)xb.x; u.s[5] = (_Float16)xb.y;
        u.s[6] = (_Float16)xb.z; u.s[7] = (_Float16)xb.w;
        ((uint4*)dstb)[srow * 32 + (sc ^ (srow & 7))] = u.v; // XOR-swizzled 16B unit
    };

    // compute tile from Ab (fp16) + store UV8 rows [t*32, +32)
    auto work = [&](const _Float16* Ab, int t) {
        const h8v* A8 = (const h8v*)Ab;
        f32x4 acc[2][2] = {};
#pragma unroll
        for (int ks = 0; ks < 8; ++ks) {
            h8v af[2];
#pragma unroll
            for (int mt = 0; mt < 2; ++mt) {
                int row = mt * 16 + (lane & 15);
                int U   = (ks * 4 + (lane >> 4)) ^ (row & 7);
                af[mt]  = A8[row * 32 + U];
            }
#pragma unroll
            for (int mt = 0; mt < 2; ++mt)
#pragma unroll
                for (int ntl = 0; ntl < 2; ++ntl)
                    acc[mt][ntl] = __builtin_amdgcn_mfma_f32_16x16x32_f16(
                        af[mt], barr[ks][ntl], acc[mt][ntl], 0, 0, 0);
        }
        // store: 2 stored-cols per row per lane -> one fp8-packed ushort
#pragma unroll
        for (int mt = 0; mt < 2; ++mt) {
#pragma unroll
            for (int r = 0; r < 4; ++r) {
                int row = t * MT2 + mt * 16 + ((lane >> 4) << 2) + r;
                float h0 = acc[mt][0][r] + b1v[0];
                float h1 = acc[mt][1][r] + b1v[1];
                int w = __builtin_amdgcn_cvt_pk_fp8_f32(h0, h1, 0, false);
                *(unsigned short*)(UV8 + (size_t)row * 512 + wave * 32 + (lane & 15) * 2)
                    = (unsigned short)w;
            }
        }
    };

    int tile = blockIdx.x;                                   // grid 256 <= NT2 always
    load_regs(tile);
    put_tile(A0h);
    __syncthreads();                                         // A0 ready

    for (;;) {
        int n1 = tile + GEMM_GRID;
        bool h1 = n1 < NT2;
        if (h1) load_regs(n1);                               // loads fly under work
        work(A0h, tile);
        if (!h1) return;
        put_tile(A1h);                                       // disjoint buffer, no barrier
        __syncthreads();                                     // A1 ready; A0 reads done

        int n2 = n1 + GEMM_GRID;
        bool h2 = n2 < NT2;
        if (h2) load_regs(n2);
        work(A1h, n1);
        if (!h2) return;
        put_tile(A0h);
        __syncthreads();                                     // A0 ready; A1 reads done
        tile = n2;
    }
}

// ---- edge pass v7: fp8 UV, all-f32 MLP; col(t) for the v11/v12 store layout
__global__ __launch_bounds__(256) void edge_out7(
    const unsigned char* __restrict__ UV8,
    const int* __restrict__ ei,
    const float* __restrict__ W2,
    const float* __restrict__ b2,
    float* __restrict__ out)
{
    const int tid = threadIdx.x;
    const int q   = tid & 31;
    const int g   = tid >> 5;
    long e = (long)blockIdx.x * 64 + g * 8;
    if (e > NEDGES - 8) e = NEDGES - 8;                      // clamp (dup writes benign)

    int4 sa = *(const int4*)(ei + e);
    int4 sb = *(const int4*)(ei + e + 4);
    int4 da = *(const int4*)(ei + NEDGES + e);
    int4 db = *(const int4*)(ei + NEDGES + e + 4);

    float w2f[8];
#pragma unroll
    for (int jj = 0; jj < 8; ++jj) {
        int t   = q * 8 + jj;
        int col = (t & ~31) | (((t & 1) << 4) | ((t >> 1) & 15));
        w2f[jj] = W2[col];
    }

    const unsigned char* up = UV8 + q * 8;

    int s[8] = {sa.x, sa.y, sa.z, sa.w, sb.x, sb.y, sb.z, sb.w};
    int d[8] = {da.x, da.y, da.z, da.w, db.x, db.y, db.z, db.w};

    uint2 uu[8], vv[8];
#pragma unroll
    for (int ed = 0; ed < 8; ++ed) {
        uu[ed] = *(const uint2*)(up + (size_t)s[ed] * 512);
        vv[ed] = *(const uint2*)(up + (size_t)d[ed] * 512 + 256);
    }

    float z[8] = {};
#pragma unroll
    for (int ed = 0; ed < 8; ++ed) {
        f32x2 u01 = __builtin_amdgcn_cvt_pk_f32_fp8((int)uu[ed].x, false);
        f32x2 u23 = __builtin_amdgcn_cvt_pk_f32_fp8((int)uu[ed].x, true);
        f32x2 u45 = __builtin_amdgcn_cvt_pk_f32_fp8((int)uu[ed].y, false);
        f32x2 u67 = __builtin_amdgcn_cvt_pk_f32_fp8((int)uu[ed].y, true);
        f32x2 v01 = __builtin_amdgcn_cvt_pk_f32_fp8((int)vv[ed].x, false);
        f32x2 v23 = __builtin_amdgcn_cvt_pk_f32_fp8((int)vv[ed].x, true);
        f32x2 v45 = __builtin_amdgcn_cvt_pk_f32_fp8((int)vv[ed].y, false);
        f32x2 v67 = __builtin_amdgcn_cvt_pk_f32_fp8((int)vv[ed].y, true);
        float h[8];
        h[0] = u01[0] + v01[0]; h[1] = u01[1] + v01[1];
        h[2] = u23[0] + v23[0]; h[3] = u23[1] + v23[1];
        h[4] = u45[0] + v45[0]; h[5] = u45[1] + v45[1];
        h[6] = u67[0] + v67[0]; h[7] = u67[1] + v67[1];
        float acc = 0.f;
#pragma unroll
        for (int jj = 0; jj < 8; ++jj)
            acc = fmaf(fmaxf(h[jj], 0.0f), w2f[jj], acc);
        z[ed] = acc;
    }
#pragma unroll
    for (int m = 1; m < 32; m <<= 1) {
#pragma unroll
        for (int ed = 0; ed < 8; ++ed)
            z[ed] += __shfl_xor(z[ed], m, 32);
    }
    if (q < 8) {
        float zq = z[0];
#pragma unroll
        for (int ed = 1; ed < 8; ++ed)
            if (q == ed) zq = z[ed];
        out[e + q] = 1.0f / (1.0f + expf(-(zq + b2[0])));
    }
}

// ======================= minimal fallback (tiny ws) =========================
__global__ void cvt_w1_r1(const float* __restrict__ W1, unsigned short* __restrict__ Bsw) {
    int t = blockIdx.x * 256 + threadIdx.x;
    if (t >= 16 * 16 * 64) return;
    int lane = t & 63, nt = (t >> 6) & 15, kt = t >> 10;
    int n = nt * 16 + (lane & 15);
    int k = kt * 32 + ((lane >> 4) << 3);
    const float* src = W1 + (size_t)n * K2 + k;
    union { unsigned short s[8]; uint4 v; } u;
#pragma unroll
    for (int j = 0; j < 8; ++j) u.s[j] = f2bf(src[j]);
    ((uint4*)Bsw)[t] = u.v;
}

__global__ __launch_bounds__(256) void edge_mlp_fb(
    const float* __restrict__ xf, const int* __restrict__ ei,
    const unsigned short* __restrict__ Bsw, const float* __restrict__ b1,
    const float* __restrict__ W2, const float* __restrict__ b2,
    float* __restrict__ out)
{
    __shared__ __align__(16) unsigned short Asw[8 * 4 * 64 * 8];
    __shared__ float es[64];
    const int tid = threadIdx.x, lane = tid & 63, wave = tid >> 6;
    const int e0 = blockIdx.x * 64;
    if (tid < 64) es[tid] = 0.0f;
    f32x4 acc[4][4] = {};
    const bf16x8* A8 = (const bf16x8*)Asw;
    const bf16x8* B8 = (const bf16x8*)Bsw;
    for (int h = 0; h < 2; ++h) {
#pragma unroll
        for (int i = 0; i < 8; ++i) {
            int m = i * 8 + wave * 2 + (lane >> 5);
            int e = e0 + m;
            int ee = (e < NEDGES) ? e : 0;
            int node = ei[(size_t)h * NEDGES + ee];
            int chunk = lane & 31;
            const float4* p = (const float4*)(xf + ((size_t)node << 8) + (chunk << 3));
            float4 a = p[0], bq = p[1];
            union { unsigned short s[8]; uint4 v4; } u;
            u.s[0] = f2bf(a.x);  u.s[1] = f2bf(a.y);  u.s[2] = f2bf(a.z);  u.s[3] = f2bf(a.w);
            u.s[4] = f2bf(bq.x); u.s[5] = f2bf(bq.y); u.s[6] = f2bf(bq.z); u.s[7] = f2bf(bq.w);
            int ktl = chunk >> 2, qq = chunk & 3;
            int u16 = ((ktl * 4 + (m >> 4)) << 6) + (qq << 4) + (m & 15);
            u16 ^= (u16 >> 8) & 7;
            ((uint4*)Asw)[u16] = u.v4;
        }
        __syncthreads();
#pragma unroll
        for (int kt = 0; kt < 8; ++kt) {
            bf16x8 af[4], bfr[4];
#pragma unroll
            for (int mt = 0; mt < 4; ++mt) {
                int u16 = ((kt * 4 + mt) << 6) + lane;
                u16 ^= (u16 >> 8) & 7;
                af[mt] = A8[u16];
            }
#pragma unroll
            for (int nt = 0; nt < 4; ++nt)
                bfr[nt] = B8[(((h * 8 + kt) << 4) + (wave << 2) + nt) * 64 + lane];
#pragma unroll
            for (int mt = 0; mt < 4; ++mt)
#pragma unroll
                for (int nt = 0; nt < 4; ++nt)
                    acc[mt][nt] = __builtin_amdgcn_mfma_f32_16x16x32_bf16(
                        af[mt], bfr[nt], acc[mt][nt], 0, 0, 0);
        }
        __syncthreads();
    }
    float w2v[4], b1v[4];
#pragma unroll
    for (int nt = 0; nt < 4; ++nt) {
        int n = (wave << 6) + (nt << 4) + (lane & 15);
        w2v[nt] = W2[n]; b1v[nt] = b1[n];
    }
#pragma unroll
    for (int mt = 0; mt < 4; ++mt) {
#pragma unroll
        for (int r = 0; r < 4; ++r) {
            float p = 0.0f;
#pragma unroll
            for (int nt = 0; nt < 4; ++nt) {
                float hv = acc[mt][nt][r] + b1v[nt];
                p = fmaf(fmaxf(hv, 0.0f), w2v[nt], p);
            }
            p += __shfl_xor(p, 1, 16);
            p += __shfl_xor(p, 2, 16);
            p += __shfl_xor(p, 4, 16);
            p += __shfl_xor(p, 8, 16);
            if ((lane & 15) == 0)
                atomicAdd(&es[(mt << 4) + ((lane >> 4) << 2) + r], p);
        }
    }
    __syncthreads();
    if (tid < 64) {
        int e = e0 + tid;
        if (e < NEDGES) out[e] = 1.0f / (1.0f + expf(-(es[tid] + b2[0])));
    }
}

// ============================== launch ======================================
extern "C" void kernel_launch(void* const* d_in, const int* in_sizes, int n_in,
                              void* d_out, int out_size, void* d_ws, size_t ws_size,
                              hipStream_t stream) {
    const float* x  = (const float*)d_in[0];
    const int*   ei = (const int*)d_in[1];
    const float* W1 = (const float*)d_in[2];
    const float* b1 = (const float*)d_in[3];
    const float* W2 = (const float*)d_in[4];
    const float* b2 = (const float*)d_in[5];
    float* out = (float*)d_out;

    const size_t BSW_BYTES = 1 << 18;                           // 256 KB
    const size_t UV8_BYTES = (size_t)NNODES * 512;              // 51.2 MB fp8
    const size_t NEED_A = BSW_BYTES + UV8_BYTES;

    if (ws_size >= NEED_A) {
        _Float16*      Bsw = (_Float16*)d_ws;
        unsigned char* UV8 = (unsigned char*)d_ws + BSW_BYTES;
        cvt_w1h<<<64, 256, 0, stream>>>(W1, Bsw);
        node_gemm12<<<GEMM_GRID, 1024, 0, stream>>>(x, Bsw, b1, UV8);
        edge_out7<<<(NEDGES + 63) / 64, 256, 0, stream>>>(UV8, ei, W2, b2, out);
    } else {
        unsigned short* Bsw = (unsigned short*)d_ws;
        cvt_w1_r1<<<64, 256, 0, stream>>>(W1, Bsw);
        edge_mlp_fb<<<(NEDGES + 63) / 64, 256, 0, stream>>>(x, ei, Bsw, b1, W2, b2, out);
    }
}